// Round 14
// baseline (5908.051 us; speedup 1.0000x reference)
//
#include <hip/hip_runtime.h>

// SentimentNet on MI355X — round 14: producer fused INSIDE the 256 proven
// cooperative blocks (1024 threads: waves 0-7 lstm, waves 8-15 xproj).
//
// r11-r13 post-mortem: absmax byte-identical across 3 different binaries +
// consistent with out==dec_b => the 512-block cooperative launch silently
// FAILED (limit ~256 for 512-thr blocks; harness ignores the error). All
// three "fixes" patched a kernel that never ran.
// This round: keep the proven 256-block cooperative shape. Each block gets
// 8 producer waves that compute xproj for THIS block's own 64 gate-rows x
// its team's 8 batches (data never leaves the block):
//  - producer mirrors the lstm dot: W_ih register-stationary (64/lane),
//    emb broadcast via readlane, k-chunk per wave
//  - both paths hit the SAME single __syncthreads per phase -> barrier
//    counts match by construction (no tags, no flags, no deadlock)
//  - step s+1 produced during step s; LDS xpF parity handoff; prologue
//    phase-pair at s=-1 fills xproj[0]
// Deleted: serial xproj kernel (~550us), 262MB xproj array + its traffic,
// done protocol. lstm waves s_setprio(1) (producer fills idle slots).

#define S_LEN 500
#define BATCH 64
#define EDIM 512
#define HDIM 512
#define TEAMS 8
#define TB 8
#define NTHREADS 1024
#define NBLOCKS 256

typedef unsigned long long ull;

// workspace layout (bytes)
#define STATES_BYTES ((size_t)S_LEN * BATCH * HDIM * 4)   // 65,536,000
#define HBUF_OFF     STATES_BYTES
#define HBUF_BYTES   ((size_t)2 * TEAMS * TB * HDIM * 8)  // 524,288 (ull)
#define PART_OFF     (HBUF_OFF + HBUF_BYTES)
#define PART_BYTES   (4 * S_LEN * BATCH * 4)              // 512,000

__global__ __launch_bounds__(NTHREADS, 4) void fused_lstm(
    const int* __restrict__ idx, const float* __restrict__ emb,
    const float* __restrict__ W_ih, const float* __restrict__ b_ih,
    const float* __restrict__ b_hh, const float* __restrict__ W_hh,
    float* __restrict__ states, ull* __restrict__ h_buf) {
  __shared__ float red[2][8][4][65];   // lstm k-partials [G][wave][b'][row]
  __shared__ float red2[2][8][4][64];  // producer k-partials [G][chunk][b'][row]
  __shared__ float xpF[2][8][72];      // xproj handoff [par][batch][row]

  const int tid  = threadIdx.x;
  const int team = blockIdx.x & 7;           // XCD-local teams
  const int wg   = blockIdx.x >> 3;          // 0..31 -> units [16wg, 16wg+16)
  const int lw   = tid >> 6;                 // wave 0..15
  const int l    = tid & 63;                 // lane

  // this lane's gate-row: g = 16wg + (l&15) + 512*(l>>4)
  const int g = 16 * wg + (l & 15) + 512 * (l >> 4);

  if (lw < 8) {
    // ================= lstm waves (r8 verbatim structure) =================
    __builtin_amdgcn_s_setprio(1);
    const int wv = lw;                       // k chunk [64wv, 64wv+64)
    float whh[64];
    {
      const float4* phh = (const float4*)(W_hh + (size_t)g * HDIM + (size_t)wv * 64);
#pragma unroll
      for (int j = 0; j < 16; ++j) {
        float4 v = phh[j];
        whh[4*j+0] = v.x; whh[4*j+1] = v.y; whh[4*j+2] = v.z; whh[4*j+3] = v.w;
      }
    }
    const int gu = l & 15, gbl = l >> 4;
    const int unit = 16 * wg + gu;
    float c_state = 0.f;

    for (int s = -1; s < S_LEN; ++s) {
      const int par = s & 1, par2 = (s + 1) & 1;
#pragma unroll
      for (int G = 0; G < 2; ++G) {
        float acc0 = 0.f, acc1 = 0.f, acc2 = 0.f, acc3 = 0.f;
        if (s > 0) {
          // tagged retry-load: lane l holds h[64wv+l] for group G's 4 batches
          const ull* hb = h_buf + (((size_t)par * TEAMS + team) * TB + G * 4) * HDIM
                          + (size_t)64 * wv + l;
          ull r0, r1, r2, r3;
          int spins = 0;
          for (;;) {
            r0 = __hip_atomic_load(hb + 0 * HDIM, __ATOMIC_RELAXED, __HIP_MEMORY_SCOPE_AGENT);
            r1 = __hip_atomic_load(hb + 1 * HDIM, __ATOMIC_RELAXED, __HIP_MEMORY_SCOPE_AGENT);
            r2 = __hip_atomic_load(hb + 2 * HDIM, __ATOMIC_RELAXED, __HIP_MEMORY_SCOPE_AGENT);
            r3 = __hip_atomic_load(hb + 3 * HDIM, __ATOMIC_RELAXED, __HIP_MEMORY_SCOPE_AGENT);
            bool ok = ((int)(r0 >> 32) == s) & ((int)(r1 >> 32) == s) &
                      ((int)(r2 >> 32) == s) & ((int)(r3 >> 32) == s);
            if (__all(ok)) break;
            __builtin_amdgcn_s_sleep(1);
            if (++spins > (1 << 18)) break;  // hang guard only
          }
          const int h0 = (int)(unsigned)r0, h1 = (int)(unsigned)r1;
          const int h2 = (int)(unsigned)r2, h3 = (int)(unsigned)r3;
#pragma unroll
          for (int k = 0; k < 64; ++k) {
            const float wk = whh[k];
            acc0 = fmaf(wk, __int_as_float(__builtin_amdgcn_readlane(h0, k)), acc0);
            acc1 = fmaf(wk, __int_as_float(__builtin_amdgcn_readlane(h1, k)), acc1);
            acc2 = fmaf(wk, __int_as_float(__builtin_amdgcn_readlane(h2, k)), acc2);
            acc3 = fmaf(wk, __int_as_float(__builtin_amdgcn_readlane(h3, k)), acc3);
          }
        }
        if (s >= 0) {
          red[G][wv][0][l] = acc0;
          red[G][wv][1][l] = acc1;
          red[G][wv][2][l] = acc2;
          red[G][wv][3][l] = acc3;
        }
        __syncthreads();
        if (s >= 0 && wv == G) {
          // reduce + xproj (from LDS handoff) + gates + publish
          float z0 = xpF[par][G * 4 + gbl][gu +  0];
          float z1 = xpF[par][G * 4 + gbl][gu + 16];
          float z2 = xpF[par][G * 4 + gbl][gu + 32];
          float z3 = xpF[par][G * 4 + gbl][gu + 48];
#pragma unroll
          for (int w2 = 0; w2 < 8; ++w2) {
            z0 += red[G][w2][gbl][gu +  0];
            z1 += red[G][w2][gbl][gu + 16];
            z2 += red[G][w2][gbl][gu + 32];
            z3 += red[G][w2][gbl][gu + 48];
          }
          float i_ = 1.f / (1.f + expf(-z0));
          float f_ = 1.f / (1.f + expf(-z1));
          float g_ = tanhf(z2);
          float o_ = 1.f / (1.f + expf(-z3));
          c_state = f_ * c_state + i_ * g_;
          float h_ = o_ * tanhf(c_state);
          ull pv = ((ull)(unsigned)(s + 1) << 32) | __float_as_uint(h_);
          __hip_atomic_store(
              &h_buf[(((size_t)par2 * TEAMS + team) * TB + G * 4 + gbl) * HDIM + unit],
              pv, __ATOMIC_RELAXED, __HIP_MEMORY_SCOPE_AGENT);
          states[((size_t)s * BATCH + team * TB + G * 4 + gbl) * HDIM + unit] = h_;
        }
        // no trailing barrier: red[G]/red2[G]/xpF reuse separated by the
        // next phases' barriers (r8 transitive argument, G-parity buffers).
      }
    }
  } else {
    // ================= producer waves: xproj for THIS block ===============
    const int pw = lw - 8;                   // k chunk [64pw, 64pw+64)
    float wih[64];
    {
      const float4* pih = (const float4*)(W_ih + (size_t)g * EDIM + (size_t)pw * 64);
#pragma unroll
      for (int j = 0; j < 16; ++j) {
        float4 v = pih[j];
        wih[4*j+0] = v.x; wih[4*j+1] = v.y; wih[4*j+2] = v.z; wih[4*j+3] = v.w;
      }
    }
    const float bias = b_ih[g] + b_hh[g];    // this lane's output row

    for (int s = -1; s < S_LEN; ++s) {
#pragma unroll
      for (int G = 0; G < 2; ++G) {
        const int sp = s + 1;                // step being produced
        if (sp < S_LEN) {
          // partials for step sp, batches G*4..G*4+3
          const int b0 = team * TB + G * 4;
          const int r0i = idx[sp * BATCH + b0 + 0];
          const int r1i = idx[sp * BATCH + b0 + 1];
          const int r2i = idx[sp * BATCH + b0 + 2];
          const int r3i = idx[sp * BATCH + b0 + 3];
          const int e0 = __float_as_int(emb[(size_t)r0i * EDIM + 64 * pw + l]);
          const int e1 = __float_as_int(emb[(size_t)r1i * EDIM + 64 * pw + l]);
          const int e2 = __float_as_int(emb[(size_t)r2i * EDIM + 64 * pw + l]);
          const int e3 = __float_as_int(emb[(size_t)r3i * EDIM + 64 * pw + l]);
          float a0 = 0.f, a1 = 0.f, a2 = 0.f, a3 = 0.f;
#pragma unroll
          for (int k = 0; k < 64; ++k) {
            const float wk = wih[k];
            a0 = fmaf(wk, __int_as_float(__builtin_amdgcn_readlane(e0, k)), a0);
            a1 = fmaf(wk, __int_as_float(__builtin_amdgcn_readlane(e1, k)), a1);
            a2 = fmaf(wk, __int_as_float(__builtin_amdgcn_readlane(e2, k)), a2);
            a3 = fmaf(wk, __int_as_float(__builtin_amdgcn_readlane(e3, k)), a3);
          }
          red2[G][pw][0][l] = a0;
          red2[G][pw][1][l] = a1;
          red2[G][pw][2][l] = a2;
          red2[G][pw][3][l] = a3;
        }
        __syncthreads();
        if (sp < S_LEN && pw < 4) {
          // reduce batch G*4+pw over the 8 k-chunks, add bias, hand off
          float z = bias;
#pragma unroll
          for (int c = 0; c < 8; ++c) z += red2[G][c][pw][l];
          xpF[sp & 1][G * 4 + pw][l] = z;
        }
      }
    }
  }
}

// ---------------- attention GEMM: tanh(states@W_word + b_word) @ w_proj ----------------
#define ATP 132
__global__ __launch_bounds__(256) void attn_gemm(
    const float* __restrict__ states, const float* __restrict__ W_word,
    const float* __restrict__ b_word, const float* __restrict__ w_proj,
    float* __restrict__ part) {
  __shared__ float At[16][ATP];   // A transposed tile [k][m]
  __shared__ float Bt[16][ATP];   // B tile [k][n]
  __shared__ float redl[128][17];

  const int tid = threadIdx.x;
  const int m0 = blockIdx.x * 128;   // token tile
  const int n0 = blockIdx.y * 128;   // tanh-dim tile
  const int ty = tid >> 4, tx = tid & 15;

  float acc[8][8];
#pragma unroll
  for (int i = 0; i < 8; ++i)
#pragma unroll
    for (int j = 0; j < 8; ++j) acc[i][j] = 0.f;

  for (int k0 = 0; k0 < 512; k0 += 16) {
#pragma unroll
    for (int it = 0; it < 2; ++it) {
      int m = (tid >> 2) + 64 * it;
      int kq = tid & 3;
      float4 v = *(const float4*)&states[(size_t)(m0 + m) * 512 + k0 + 4 * kq];
      At[4 * kq + 0][m] = v.x; At[4 * kq + 1][m] = v.y;
      At[4 * kq + 2][m] = v.z; At[4 * kq + 3][m] = v.w;
    }
#pragma unroll
    for (int it = 0; it < 2; ++it) {
      int kr = (tid >> 5) + 8 * it;
      int nq = tid & 31;
      float4 v = *(const float4*)&W_word[(size_t)(k0 + kr) * 512 + n0 + 4 * nq];
      *(float4*)&Bt[kr][4 * nq] = v;
    }
    __syncthreads();
#pragma unroll
    for (int kk = 0; kk < 16; ++kk) {
      float4 a0 = *(const float4*)&At[kk][ty * 8];
      float4 a1 = *(const float4*)&At[kk][ty * 8 + 4];
      float4 b0 = *(const float4*)&Bt[kk][tx * 8];
      float4 b1 = *(const float4*)&Bt[kk][tx * 8 + 4];
      float av[8] = {a0.x, a0.y, a0.z, a0.w, a1.x, a1.y, a1.z, a1.w};
      float bv[8] = {b0.x, b0.y, b0.z, b0.w, b1.x, b1.y, b1.z, b1.w};
#pragma unroll
      for (int i = 0; i < 8; ++i)
#pragma unroll
        for (int j = 0; j < 8; ++j) acc[i][j] = fmaf(av[i], bv[j], acc[i][j]);
    }
    __syncthreads();
  }
  float bw[8], wp[8];
  {
    float4 v0 = *(const float4*)&b_word[n0 + tx * 8];
    float4 v1 = *(const float4*)&b_word[n0 + tx * 8 + 4];
    bw[0]=v0.x; bw[1]=v0.y; bw[2]=v0.z; bw[3]=v0.w; bw[4]=v1.x; bw[5]=v1.y; bw[6]=v1.z; bw[7]=v1.w;
    float4 u0 = *(const float4*)&w_proj[n0 + tx * 8];
    float4 u1 = *(const float4*)&w_proj[n0 + tx * 8 + 4];
    wp[0]=u0.x; wp[1]=u0.y; wp[2]=u0.z; wp[3]=u0.w; wp[4]=u1.x; wp[5]=u1.y; wp[6]=u1.z; wp[7]=u1.w;
  }
#pragma unroll
  for (int i = 0; i < 8; ++i) {
    float rs = 0.f;
#pragma unroll
    for (int j = 0; j < 8; ++j) rs += tanhf(acc[i][j] + bw[j]) * wp[j];
    redl[ty * 8 + i][tx] = rs;
  }
  __syncthreads();
  if (tid < 128) {
    float ssum = 0.f;
#pragma unroll
    for (int x = 0; x < 16; ++x) ssum += redl[tid][x];
    part[(size_t)blockIdx.y * (S_LEN * BATCH) + m0 + tid] = ssum;
  }
}

// ---------------- softmax over S + pooled sum + decode ----------------
__global__ __launch_bounds__(256) void softmax_pool_decode(
    const float* __restrict__ part, const float* __restrict__ states,
    const float* __restrict__ dec_W, const float* __restrict__ dec_b,
    float* __restrict__ out) {
  const int b = blockIdx.x;
  const int tid = threadIdx.x;
  __shared__ float sc[S_LEN];
  __shared__ float pool[HDIM];
  __shared__ float redm[256];

  for (int s = tid; s < S_LEN; s += 256) {
    int t = s * BATCH + b;
    sc[s] = part[t] + part[S_LEN * BATCH + t] + part[2 * S_LEN * BATCH + t] +
            part[3 * S_LEN * BATCH + t];
  }
  __syncthreads();
  float m = -1e30f;
  for (int s = tid; s < S_LEN; s += 256) m = fmaxf(m, sc[s]);
  redm[tid] = m; __syncthreads();
  for (int o = 128; o > 0; o >>= 1) {
    if (tid < o) redm[tid] = fmaxf(redm[tid], redm[tid + o]);
    __syncthreads();
  }
  const float gmax = redm[0];
  __syncthreads();
  float lsum = 0.f;
  for (int s = tid; s < S_LEN; s += 256) { float e = expf(sc[s] - gmax); sc[s] = e; lsum += e; }
  redm[tid] = lsum; __syncthreads();
  for (int o = 128; o > 0; o >>= 1) {
    if (tid < o) redm[tid] += redm[tid + o];
    __syncthreads();
  }
  const float inv = 1.f / redm[0];
  __syncthreads();
  for (int h = tid; h < HDIM; h += 256) {
    float a = 0.f;
    for (int s = 0; s < S_LEN; ++s)
      a = fmaf(sc[s], states[((size_t)s * BATCH + b) * HDIM + h], a);
    pool[h] = a * inv;
  }
  __syncthreads();
  const int lcls = tid >> 7, ch = tid & 127;
  float p = 0.f;
#pragma unroll
  for (int j = 0; j < 4; ++j)
    p = fmaf(pool[ch * 4 + j], dec_W[lcls * HDIM + ch * 4 + j], p);
  redm[tid] = p; __syncthreads();
  for (int o = 64; o > 0; o >>= 1) {
    if (ch < o) redm[tid] += redm[tid + o];
    __syncthreads();
  }
  if (ch == 0) out[b * 2 + lcls] = redm[tid] + dec_b[lcls];
}

extern "C" void kernel_launch(void* const* d_in, const int* in_sizes, int n_in,
                              void* d_out, int out_size, void* d_ws, size_t ws_size,
                              hipStream_t stream) {
  const int*   idx    = (const int*)d_in[0];
  // d_in[1] = text_lengths: unused by the reference
  const float* emb    = (const float*)d_in[2];
  const float* W_ih   = (const float*)d_in[3];
  const float* W_hh   = (const float*)d_in[4];
  const float* b_ih   = (const float*)d_in[5];
  const float* b_hh   = (const float*)d_in[6];
  const float* W_word = (const float*)d_in[7];
  const float* b_word = (const float*)d_in[8];
  const float* w_proj = (const float*)d_in[9];
  const float* dec_W  = (const float*)d_in[10];
  const float* dec_b  = (const float*)d_in[11];
  float* out = (float*)d_out;

  char* ws = (char*)d_ws;
  float* states = (float*)ws;
  ull*   h_buf  = (ull*)(ws + HBUF_OFF);
  float* part   = (float*)(ws + PART_OFF);

  // tags must start invalid each launch (prevents cross-replay tag collision)
  hipMemsetAsync(h_buf, 0, HBUF_BYTES, stream);

  // fused recurrence + in-block xproj producer (proven 256-block cooperative)
  void* args[] = {(void*)&idx, (void*)&emb, (void*)&W_ih, (void*)&b_ih,
                  (void*)&b_hh, (void*)&W_hh, (void*)&states, (void*)&h_buf};
  hipLaunchCooperativeKernel(fused_lstm, dim3(NBLOCKS), dim3(NTHREADS), args, 0, stream);

  attn_gemm<<<dim3(250, 4), 256, 0, stream>>>(states, W_word, b_word, w_proj, part);
  softmax_pool_decode<<<64, 256, 0, stream>>>(part, states, dec_W, dec_b, out);
}

// Round 15
// 3140.082 us; speedup vs baseline: 1.8815x; 1.8815x over previous
//
#include <hip/hip_runtime.h>

// SentimentNet on MI355X — round 15: revert to r8 (proven best, total 3.12ms)
// + one fallback-safe tweak: step-top prefetch of all 8 tagged h words so
// phase G=1's LLC detect latency hides under phase G=0's dot+barrier+gates.
//
// r14 post-mortem: in-block producer fusion couples emb-gather latency +
// producer VALU issue into the barrier rhythm -> 2.6x regression. r9-r14
// establish r8's structure as the local optimum; this round only hoists
// loads within a wave (retry fallback identical to r8 => worst case == r8).

#define S_LEN 500
#define BATCH 64
#define EDIM 512
#define HDIM 512
#define TEAMS 8
#define WGS_PER_TEAM 32
#define TB 8
#define NBLOCKS (TEAMS * WGS_PER_TEAM)
#define NTHREADS 512

typedef unsigned long long ull;

// workspace layout (bytes)
#define XPROJ_BYTES  ((size_t)S_LEN * 2048 * BATCH * 4)   // 262,144,000
#define STATES_OFF   XPROJ_BYTES
#define STATES_BYTES ((size_t)S_LEN * BATCH * HDIM * 4)   // 65,536,000
#define HBUF_OFF     (STATES_OFF + STATES_BYTES)
#define HBUF_BYTES   ((size_t)2 * TEAMS * TB * HDIM * 8)  // 524,288 (ull)
#define PART_OFF     (HBUF_OFF + HBUF_BYTES)
#define PART_BYTES   (4 * S_LEN * BATCH * 4)              // 512,000

// ---------------- xproj GEMM: xproj[s][team][g][tb] = W_ih[g,:]·emb[idx[s,b],:] + b_ih[g]+b_hh[g]
__global__ __launch_bounds__(256) void xproj_gemm(
    const int* __restrict__ idx, const float* __restrict__ emb,
    const float* __restrict__ W_ih, const float* __restrict__ b_ih,
    const float* __restrict__ b_hh, float* __restrict__ xproj) {
  __shared__ float At[16][132];   // [k][g]
  __shared__ float Bt[16][132];   // [k][sb]
  __shared__ int sidx[128];

  const int tid = threadIdx.x;
  const int sb0 = blockIdx.x * 128;   // (s,b) flat tile
  const int g0  = blockIdx.y * 128;   // gate-row tile
  if (tid < 128) sidx[tid] = idx[sb0 + tid];

  const int ty = tid >> 4, tx = tid & 15;
  const int ra = tid & 127, pp = tid >> 7;   // row/col within tile, 8-k part

  float acc[8][8];
#pragma unroll
  for (int i = 0; i < 8; ++i)
#pragma unroll
    for (int j = 0; j < 8; ++j) acc[i][j] = 0.f;

  __syncthreads();   // sidx ready

  for (int k0 = 0; k0 < 512; k0 += 16) {
    const float* pa = &W_ih[(size_t)(g0 + ra) * 512 + k0 + 8 * pp];
    float4 a0 = *(const float4*)pa, a1 = *(const float4*)(pa + 4);
    const float* pb = &emb[(size_t)sidx[ra] * 512 + k0 + 8 * pp];
    float4 b0 = *(const float4*)pb, b1 = *(const float4*)(pb + 4);
    At[8*pp+0][ra]=a0.x; At[8*pp+1][ra]=a0.y; At[8*pp+2][ra]=a0.z; At[8*pp+3][ra]=a0.w;
    At[8*pp+4][ra]=a1.x; At[8*pp+5][ra]=a1.y; At[8*pp+6][ra]=a1.z; At[8*pp+7][ra]=a1.w;
    Bt[8*pp+0][ra]=b0.x; Bt[8*pp+1][ra]=b0.y; Bt[8*pp+2][ra]=b0.z; Bt[8*pp+3][ra]=b0.w;
    Bt[8*pp+4][ra]=b1.x; Bt[8*pp+5][ra]=b1.y; Bt[8*pp+6][ra]=b1.z; Bt[8*pp+7][ra]=b1.w;
    __syncthreads();
#pragma unroll
    for (int kk = 0; kk < 16; ++kk) {
      float4 x0 = *(const float4*)&At[kk][ty * 8];
      float4 x1 = *(const float4*)&At[kk][ty * 8 + 4];
      float4 y0 = *(const float4*)&Bt[kk][tx * 8];
      float4 y1 = *(const float4*)&Bt[kk][tx * 8 + 4];
      float av[8] = {x0.x, x0.y, x0.z, x0.w, x1.x, x1.y, x1.z, x1.w};
      float bv[8] = {y0.x, y0.y, y0.z, y0.w, y1.x, y1.y, y1.z, y1.w};
#pragma unroll
      for (int i = 0; i < 8; ++i)
#pragma unroll
        for (int j = 0; j < 8; ++j) acc[i][j] = fmaf(av[i], bv[j], acc[i][j]);
    }
    __syncthreads();
  }
  // epilogue: + bias, store 8 consecutive tb per (row i): [s][team][g][tb]
  const int sbb = sb0 + tx * 8;       // first of this thread's 8 sb
  const int s  = sbb >> 6;
  const int tm = (sbb & 63) >> 3;     // team (8 consecutive sb span one team)
#pragma unroll
  for (int i = 0; i < 8; ++i) {
    const int g = g0 + ty * 8 + i;
    const float bias = b_ih[g] + b_hh[g];
    float* dst = &xproj[(((size_t)s * TEAMS + tm) * 2048 + g) * 8];
    float4 v0 = {acc[i][0] + bias, acc[i][1] + bias, acc[i][2] + bias, acc[i][3] + bias};
    float4 v1 = {acc[i][4] + bias, acc[i][5] + bias, acc[i][6] + bias, acc[i][7] + bias};
    *(float4*)dst = v0;
    *(float4*)(dst + 4) = v1;
  }
}

// ---------------- persistent recurrence (r8 + step-top h prefetch) ----------------
__global__ __launch_bounds__(NTHREADS, 1) void lstm_persistent(
    const float* __restrict__ xproj, const float* __restrict__ W_hh,
    float* __restrict__ states, ull* __restrict__ h_buf) {
  __shared__ float red[2][8][4][65];   // [group][wave][b_local][row] padded

  const int team = blockIdx.x & 7;           // XCD-local teams
  const int wg   = blockIdx.x >> 3;          // 0..31 -> units [16wg, 16wg+16)
  const int tid  = threadIdx.x;
  const int wv   = tid >> 6;                 // wave 0..7 -> k chunk [64wv, 64wv+64)
  const int l    = tid & 63;                 // lane

  // this lane's gate-row: g = 16wg + (l&15) + 512*(l>>4)
  const int g = 16 * wg + (l & 15) + 512 * (l >> 4);

  // register-stationary recurrent weights: lane's row, wave's 64-k chunk
  float whh[64];
  {
    const float4* phh = (const float4*)(W_hh + (size_t)g * HDIM + (size_t)wv * 64);
#pragma unroll
    for (int j = 0; j < 16; ++j) {
      float4 v = phh[j];
      whh[4*j+0] = v.x; whh[4*j+1] = v.y; whh[4*j+2] = v.z; whh[4*j+3] = v.w;
    }
  }

  // gate identity (waves 0,1 act): unit gu, local batch gbl (0..3)
  const int gu = l & 15, gbl = l >> 4;
  const int unit = 16 * wg + gu;
  float c_state = 0.f;
  // xproj base for this gate thread (group = wv): [s][team][g][tb]
  const float* xpbase = xproj + (size_t)(16 * wg + gu) * 8 + (wv * 4 + gbl);

  for (int s = 0; s < S_LEN; ++s) {
    const int par = s & 1, par2 = (s + 1) & 1;

    // step-top prefetch: issue all 8 batches' tagged h loads at once.
    // G=0's four are consumed immediately (same position as r8); G=1's four
    // stay in flight across phase 0 — hides one LLC latency per step.
    ull pre0 = 0, pre1 = 0, pre2 = 0, pre3 = 0;
    ull pre4 = 0, pre5 = 0, pre6 = 0, pre7 = 0;
    const ull* hb0 = h_buf + (((size_t)par * TEAMS + team) * TB) * HDIM
                     + (size_t)64 * wv + l;
    if (s > 0) {
      pre0 = __hip_atomic_load(hb0 + 0 * HDIM, __ATOMIC_RELAXED, __HIP_MEMORY_SCOPE_AGENT);
      pre1 = __hip_atomic_load(hb0 + 1 * HDIM, __ATOMIC_RELAXED, __HIP_MEMORY_SCOPE_AGENT);
      pre2 = __hip_atomic_load(hb0 + 2 * HDIM, __ATOMIC_RELAXED, __HIP_MEMORY_SCOPE_AGENT);
      pre3 = __hip_atomic_load(hb0 + 3 * HDIM, __ATOMIC_RELAXED, __HIP_MEMORY_SCOPE_AGENT);
      pre4 = __hip_atomic_load(hb0 + 4 * HDIM, __ATOMIC_RELAXED, __HIP_MEMORY_SCOPE_AGENT);
      pre5 = __hip_atomic_load(hb0 + 5 * HDIM, __ATOMIC_RELAXED, __HIP_MEMORY_SCOPE_AGENT);
      pre6 = __hip_atomic_load(hb0 + 6 * HDIM, __ATOMIC_RELAXED, __HIP_MEMORY_SCOPE_AGENT);
      pre7 = __hip_atomic_load(hb0 + 7 * HDIM, __ATOMIC_RELAXED, __HIP_MEMORY_SCOPE_AGENT);
    }

#pragma unroll
    for (int G = 0; G < 2; ++G) {
      // gate wave for G prefetches its 4 xproj values (consumed after sync)
      float xv0, xv1, xv2, xv3;
      if (wv == G) {
        const float* p = xpbase + ((size_t)s * TEAMS + team) * (2048 * 8);
        xv0 = p[0]; xv1 = p[512 * 8]; xv2 = p[1024 * 8]; xv3 = p[1536 * 8];
      }

      float acc0 = 0.f, acc1 = 0.f, acc2 = 0.f, acc3 = 0.f;
      if (s > 0) {
        // use prefetched words; fall back to r8's retry loop on stale tags
        ull r0 = (G == 0) ? pre0 : pre4;
        ull r1 = (G == 0) ? pre1 : pre5;
        ull r2 = (G == 0) ? pre2 : pre6;
        ull r3 = (G == 0) ? pre3 : pre7;
        bool ok = ((int)(r0 >> 32) == s) & ((int)(r1 >> 32) == s) &
                  ((int)(r2 >> 32) == s) & ((int)(r3 >> 32) == s);
        if (!__all(ok)) {
          const ull* hb = hb0 + (size_t)(G * 4) * HDIM;
          int spins = 0;
          for (;;) {
            r0 = __hip_atomic_load(hb + 0 * HDIM, __ATOMIC_RELAXED, __HIP_MEMORY_SCOPE_AGENT);
            r1 = __hip_atomic_load(hb + 1 * HDIM, __ATOMIC_RELAXED, __HIP_MEMORY_SCOPE_AGENT);
            r2 = __hip_atomic_load(hb + 2 * HDIM, __ATOMIC_RELAXED, __HIP_MEMORY_SCOPE_AGENT);
            r3 = __hip_atomic_load(hb + 3 * HDIM, __ATOMIC_RELAXED, __HIP_MEMORY_SCOPE_AGENT);
            ok = ((int)(r0 >> 32) == s) & ((int)(r1 >> 32) == s) &
                 ((int)(r2 >> 32) == s) & ((int)(r3 >> 32) == s);
            if (__all(ok)) break;
            __builtin_amdgcn_s_sleep(1);
            if (++spins > (1 << 18)) break;    // hang guard only
          }
        }
        const int h0 = (int)(unsigned)r0, h1 = (int)(unsigned)r1;
        const int h2 = (int)(unsigned)r2, h3 = (int)(unsigned)r3;
        // dot via wave-broadcast readlane: VALU-pipe, no LDS
#pragma unroll
        for (int k = 0; k < 64; ++k) {
          const float wk = whh[k];
          acc0 = fmaf(wk, __int_as_float(__builtin_amdgcn_readlane(h0, k)), acc0);
          acc1 = fmaf(wk, __int_as_float(__builtin_amdgcn_readlane(h1, k)), acc1);
          acc2 = fmaf(wk, __int_as_float(__builtin_amdgcn_readlane(h2, k)), acc2);
          acc3 = fmaf(wk, __int_as_float(__builtin_amdgcn_readlane(h3, k)), acc3);
        }
      }

      // publish k-partials
      red[G][wv][0][l] = acc0;
      red[G][wv][1][l] = acc1;
      red[G][wv][2][l] = acc2;
      red[G][wv][3][l] = acc3;
      __syncthreads();

      // fused reduce + gates + exchange store: gate wave G only
      if (wv == G) {
        float z0 = xv0, z1 = xv1, z2 = xv2, z3 = xv3;
#pragma unroll
        for (int w2 = 0; w2 < 8; ++w2) {
          z0 += red[G][w2][gbl][gu +  0];
          z1 += red[G][w2][gbl][gu + 16];
          z2 += red[G][w2][gbl][gu + 32];
          z3 += red[G][w2][gbl][gu + 48];
        }
        float i_ = 1.f / (1.f + expf(-z0));
        float f_ = 1.f / (1.f + expf(-z1));
        float g_ = tanhf(z2);
        float o_ = 1.f / (1.f + expf(-z3));
        c_state = f_ * c_state + i_ * g_;
        float h_ = o_ * tanhf(c_state);
        // single 8B fire-and-forget message (tag = s+1 | h bits)
        ull pv = ((ull)(unsigned)(s + 1) << 32) | __float_as_uint(h_);
        __hip_atomic_store(
            &h_buf[(((size_t)par2 * TEAMS + team) * TB + G * 4 + gbl) * HDIM + unit],
            pv, __ATOMIC_RELAXED, __HIP_MEMORY_SCOPE_AGENT);
        states[((size_t)s * BATCH + team * TB + G * 4 + gbl) * HDIM + unit] = h_;
      }
      // no trailing barrier: next phase writes red[G^1]; red[G] is re-written
      // only after the NEXT phase's syncthreads (r8 transitive argument).
    }
  }
}

// ---------------- attention GEMM: tanh(states@W_word + b_word) @ w_proj ----------------
#define ATP 132
__global__ __launch_bounds__(256) void attn_gemm(
    const float* __restrict__ states, const float* __restrict__ W_word,
    const float* __restrict__ b_word, const float* __restrict__ w_proj,
    float* __restrict__ part) {
  __shared__ float At[16][ATP];   // A transposed tile [k][m]
  __shared__ float Bt[16][ATP];   // B tile [k][n]
  __shared__ float redl[128][17];

  const int tid = threadIdx.x;
  const int m0 = blockIdx.x * 128;   // token tile
  const int n0 = blockIdx.y * 128;   // tanh-dim tile
  const int ty = tid >> 4, tx = tid & 15;

  float acc[8][8];
#pragma unroll
  for (int i = 0; i < 8; ++i)
#pragma unroll
    for (int j = 0; j < 8; ++j) acc[i][j] = 0.f;

  for (int k0 = 0; k0 < 512; k0 += 16) {
#pragma unroll
    for (int it = 0; it < 2; ++it) {
      int m = (tid >> 2) + 64 * it;
      int kq = tid & 3;
      float4 v = *(const float4*)&states[(size_t)(m0 + m) * 512 + k0 + 4 * kq];
      At[4 * kq + 0][m] = v.x; At[4 * kq + 1][m] = v.y;
      At[4 * kq + 2][m] = v.z; At[4 * kq + 3][m] = v.w;
    }
#pragma unroll
    for (int it = 0; it < 2; ++it) {
      int kr = (tid >> 5) + 8 * it;
      int nq = tid & 31;
      float4 v = *(const float4*)&W_word[(size_t)(k0 + kr) * 512 + n0 + 4 * nq];
      *(float4*)&Bt[kr][4 * nq] = v;
    }
    __syncthreads();
#pragma unroll
    for (int kk = 0; kk < 16; ++kk) {
      float4 a0 = *(const float4*)&At[kk][ty * 8];
      float4 a1 = *(const float4*)&At[kk][ty * 8 + 4];
      float4 b0 = *(const float4*)&Bt[kk][tx * 8];
      float4 b1 = *(const float4*)&Bt[kk][tx * 8 + 4];
      float av[8] = {a0.x, a0.y, a0.z, a0.w, a1.x, a1.y, a1.z, a1.w};
      float bv[8] = {b0.x, b0.y, b0.z, b0.w, b1.x, b1.y, b1.z, b1.w};
#pragma unroll
      for (int i = 0; i < 8; ++i)
#pragma unroll
        for (int j = 0; j < 8; ++j) acc[i][j] = fmaf(av[i], bv[j], acc[i][j]);
    }
    __syncthreads();
  }
  float bw[8], wp[8];
  {
    float4 v0 = *(const float4*)&b_word[n0 + tx * 8];
    float4 v1 = *(const float4*)&b_word[n0 + tx * 8 + 4];
    bw[0]=v0.x; bw[1]=v0.y; bw[2]=v0.z; bw[3]=v0.w; bw[4]=v1.x; bw[5]=v1.y; bw[6]=v1.z; bw[7]=v1.w;
    float4 u0 = *(const float4*)&w_proj[n0 + tx * 8];
    float4 u1 = *(const float4*)&w_proj[n0 + tx * 8 + 4];
    wp[0]=u0.x; wp[1]=u0.y; wp[2]=u0.z; wp[3]=u0.w; wp[4]=u1.x; wp[5]=u1.y; wp[6]=u1.z; wp[7]=u1.w;
  }
#pragma unroll
  for (int i = 0; i < 8; ++i) {
    float rs = 0.f;
#pragma unroll
    for (int j = 0; j < 8; ++j) rs += tanhf(acc[i][j] + bw[j]) * wp[j];
    redl[ty * 8 + i][tx] = rs;
  }
  __syncthreads();
  if (tid < 128) {
    float ssum = 0.f;
#pragma unroll
    for (int x = 0; x < 16; ++x) ssum += redl[tid][x];
    part[(size_t)blockIdx.y * (S_LEN * BATCH) + m0 + tid] = ssum;
  }
}

// ---------------- softmax over S + pooled sum + decode ----------------
__global__ __launch_bounds__(256) void softmax_pool_decode(
    const float* __restrict__ part, const float* __restrict__ states,
    const float* __restrict__ dec_W, const float* __restrict__ dec_b,
    float* __restrict__ out) {
  const int b = blockIdx.x;
  const int tid = threadIdx.x;
  __shared__ float sc[S_LEN];
  __shared__ float pool[HDIM];
  __shared__ float redm[256];

  for (int s = tid; s < S_LEN; s += 256) {
    int t = s * BATCH + b;
    sc[s] = part[t] + part[S_LEN * BATCH + t] + part[2 * S_LEN * BATCH + t] +
            part[3 * S_LEN * BATCH + t];
  }
  __syncthreads();
  float m = -1e30f;
  for (int s = tid; s < S_LEN; s += 256) m = fmaxf(m, sc[s]);
  redm[tid] = m; __syncthreads();
  for (int o = 128; o > 0; o >>= 1) {
    if (tid < o) redm[tid] = fmaxf(redm[tid], redm[tid + o]);
    __syncthreads();
  }
  const float gmax = redm[0];
  __syncthreads();
  float lsum = 0.f;
  for (int s = tid; s < S_LEN; s += 256) { float e = expf(sc[s] - gmax); sc[s] = e; lsum += e; }
  redm[tid] = lsum; __syncthreads();
  for (int o = 128; o > 0; o >>= 1) {
    if (tid < o) redm[tid] += redm[tid + o];
    __syncthreads();
  }
  const float inv = 1.f / redm[0];
  __syncthreads();
  for (int h = tid; h < HDIM; h += 256) {
    float a = 0.f;
    for (int s = 0; s < S_LEN; ++s)
      a = fmaf(sc[s], states[((size_t)s * BATCH + b) * HDIM + h], a);
    pool[h] = a * inv;
  }
  __syncthreads();
  const int lcls = tid >> 7, ch = tid & 127;
  float p = 0.f;
#pragma unroll
  for (int j = 0; j < 4; ++j)
    p = fmaf(pool[ch * 4 + j], dec_W[lcls * HDIM + ch * 4 + j], p);
  redm[tid] = p; __syncthreads();
  for (int o = 64; o > 0; o >>= 1) {
    if (ch < o) redm[tid] += redm[tid + o];
    __syncthreads();
  }
  if (ch == 0) out[b * 2 + lcls] = redm[tid] + dec_b[lcls];
}

extern "C" void kernel_launch(void* const* d_in, const int* in_sizes, int n_in,
                              void* d_out, int out_size, void* d_ws, size_t ws_size,
                              hipStream_t stream) {
  const int*   idx    = (const int*)d_in[0];
  // d_in[1] = text_lengths: unused by the reference
  const float* emb    = (const float*)d_in[2];
  const float* W_ih   = (const float*)d_in[3];
  const float* W_hh   = (const float*)d_in[4];
  const float* b_ih   = (const float*)d_in[5];
  const float* b_hh   = (const float*)d_in[6];
  const float* W_word = (const float*)d_in[7];
  const float* b_word = (const float*)d_in[8];
  const float* w_proj = (const float*)d_in[9];
  const float* dec_W  = (const float*)d_in[10];
  const float* dec_b  = (const float*)d_in[11];
  float* out = (float*)d_out;

  char* ws = (char*)d_ws;
  float* xproj  = (float*)ws;
  float* states = (float*)(ws + STATES_OFF);
  ull*   h_buf  = (ull*)(ws + HBUF_OFF);
  float* part   = (float*)(ws + PART_OFF);

  // tags must start invalid each launch (prevents cross-replay tag collision)
  hipMemsetAsync(h_buf, 0, HBUF_BYTES, stream);

  // 1) x-projection for all timesteps (parallel GEMM, 67 GFLOP)
  xproj_gemm<<<dim3(250, 16), 256, 0, stream>>>(idx, emb, W_ih, b_ih, b_hh, xproj);

  // 2) recurrence (persistent cooperative, proven 256-block shape)
  void* args[] = {(void*)&xproj, (void*)&W_hh, (void*)&states, (void*)&h_buf};
  hipLaunchCooperativeKernel(lstm_persistent, dim3(NBLOCKS), dim3(NTHREADS), args, 0, stream);

  // 3) attention scores + 4) softmax/pool/decode
  attn_gemm<<<dim3(250, 4), 256, 0, stream>>>(states, W_word, b_word, w_proj, part);
  softmax_pool_decode<<<64, 256, 0, stream>>>(part, states, dec_W, dec_b, out);
}

// Round 16
// 3113.312 us; speedup vs baseline: 1.8977x; 1.0086x over previous
//
#include <hip/hip_runtime.h>

// SentimentNet on MI355X — round 16: r15 + (a) red stride 65->72 (gate-wave
// reduce banks -> exact 2-way, free) + (b) two-phase parallel softmax-pool
// (512-block online-softmax partials + 64-block merge/decode).
//
// Ledger (7 structural variants): lstm step floor ~4.4us = 1.7 VALU issue
// (2x readlane penalty) + 0.9 LLC exchange + 0.8 barrier/reduce/gates.
// xproj/attn at ~85% of fp32 vector roofline. Only sub-roofline piece left:
// softmax_pool at 64 blocks -> parallelize.

#define S_LEN 500
#define BATCH 64
#define EDIM 512
#define HDIM 512
#define TEAMS 8
#define WGS_PER_TEAM 32
#define TB 8
#define NBLOCKS (TEAMS * WGS_PER_TEAM)
#define NTHREADS 512
#define NSLICE 8
#define SLICE_LEN 63              // 7*63 + 59 = 500

typedef unsigned long long ull;

// workspace layout (bytes)
#define XPROJ_BYTES  ((size_t)S_LEN * 2048 * BATCH * 4)   // 262,144,000
#define STATES_OFF   XPROJ_BYTES
#define STATES_BYTES ((size_t)S_LEN * BATCH * HDIM * 4)   // 65,536,000
#define HBUF_OFF     (STATES_OFF + STATES_BYTES)
#define HBUF_BYTES   ((size_t)2 * TEAMS * TB * HDIM * 8)  // 524,288 (ull)
#define PART_OFF     (HBUF_OFF + HBUF_BYTES)
#define PART_BYTES   (4 * S_LEN * BATCH * 4)              // 512,000
#define POOLP_OFF    (PART_OFF + PART_BYTES)
#define POOLP_BYTES  ((size_t)BATCH * NSLICE * HDIM * 4)  // 1,048,576
#define ML_OFF       (POOLP_OFF + POOLP_BYTES)
#define ML_BYTES     (BATCH * NSLICE * 2 * 4)             // 4,096

// ---------------- xproj GEMM: xproj[s][team][g][tb] = W_ih[g,:]·emb[idx[s,b],:] + b_ih[g]+b_hh[g]
__global__ __launch_bounds__(256) void xproj_gemm(
    const int* __restrict__ idx, const float* __restrict__ emb,
    const float* __restrict__ W_ih, const float* __restrict__ b_ih,
    const float* __restrict__ b_hh, float* __restrict__ xproj) {
  __shared__ float At[16][132];   // [k][g]
  __shared__ float Bt[16][132];   // [k][sb]
  __shared__ int sidx[128];

  const int tid = threadIdx.x;
  const int sb0 = blockIdx.x * 128;   // (s,b) flat tile
  const int g0  = blockIdx.y * 128;   // gate-row tile
  if (tid < 128) sidx[tid] = idx[sb0 + tid];

  const int ty = tid >> 4, tx = tid & 15;
  const int ra = tid & 127, pp = tid >> 7;   // row/col within tile, 8-k part

  float acc[8][8];
#pragma unroll
  for (int i = 0; i < 8; ++i)
#pragma unroll
    for (int j = 0; j < 8; ++j) acc[i][j] = 0.f;

  __syncthreads();   // sidx ready

  for (int k0 = 0; k0 < 512; k0 += 16) {
    const float* pa = &W_ih[(size_t)(g0 + ra) * 512 + k0 + 8 * pp];
    float4 a0 = *(const float4*)pa, a1 = *(const float4*)(pa + 4);
    const float* pb = &emb[(size_t)sidx[ra] * 512 + k0 + 8 * pp];
    float4 b0 = *(const float4*)pb, b1 = *(const float4*)(pb + 4);
    At[8*pp+0][ra]=a0.x; At[8*pp+1][ra]=a0.y; At[8*pp+2][ra]=a0.z; At[8*pp+3][ra]=a0.w;
    At[8*pp+4][ra]=a1.x; At[8*pp+5][ra]=a1.y; At[8*pp+6][ra]=a1.z; At[8*pp+7][ra]=a1.w;
    Bt[8*pp+0][ra]=b0.x; Bt[8*pp+1][ra]=b0.y; Bt[8*pp+2][ra]=b0.z; Bt[8*pp+3][ra]=b0.w;
    Bt[8*pp+4][ra]=b1.x; Bt[8*pp+5][ra]=b1.y; Bt[8*pp+6][ra]=b1.z; Bt[8*pp+7][ra]=b1.w;
    __syncthreads();
#pragma unroll
    for (int kk = 0; kk < 16; ++kk) {
      float4 x0 = *(const float4*)&At[kk][ty * 8];
      float4 x1 = *(const float4*)&At[kk][ty * 8 + 4];
      float4 y0 = *(const float4*)&Bt[kk][tx * 8];
      float4 y1 = *(const float4*)&Bt[kk][tx * 8 + 4];
      float av[8] = {x0.x, x0.y, x0.z, x0.w, x1.x, x1.y, x1.z, x1.w};
      float bv[8] = {y0.x, y0.y, y0.z, y0.w, y1.x, y1.y, y1.z, y1.w};
#pragma unroll
      for (int i = 0; i < 8; ++i)
#pragma unroll
        for (int j = 0; j < 8; ++j) acc[i][j] = fmaf(av[i], bv[j], acc[i][j]);
    }
    __syncthreads();
  }
  // epilogue: + bias, store 8 consecutive tb per (row i): [s][team][g][tb]
  const int sbb = sb0 + tx * 8;       // first of this thread's 8 sb
  const int s  = sbb >> 6;
  const int tm = (sbb & 63) >> 3;     // team (8 consecutive sb span one team)
#pragma unroll
  for (int i = 0; i < 8; ++i) {
    const int g = g0 + ty * 8 + i;
    const float bias = b_ih[g] + b_hh[g];
    float* dst = &xproj[(((size_t)s * TEAMS + tm) * 2048 + g) * 8];
    float4 v0 = {acc[i][0] + bias, acc[i][1] + bias, acc[i][2] + bias, acc[i][3] + bias};
    float4 v1 = {acc[i][4] + bias, acc[i][5] + bias, acc[i][6] + bias, acc[i][7] + bias};
    *(float4*)dst = v0;
    *(float4*)(dst + 4) = v1;
  }
}

// ---------------- persistent recurrence (r15 + stride-72 red) ----------------
__global__ __launch_bounds__(NTHREADS, 1) void lstm_persistent(
    const float* __restrict__ xproj, const float* __restrict__ W_hh,
    float* __restrict__ states, ull* __restrict__ h_buf) {
  __shared__ float red[2][8][4][72];   // [group][wave][b_local][row] stride 72

  const int team = blockIdx.x & 7;           // XCD-local teams
  const int wg   = blockIdx.x >> 3;          // 0..31 -> units [16wg, 16wg+16)
  const int tid  = threadIdx.x;
  const int wv   = tid >> 6;                 // wave 0..7 -> k chunk [64wv, 64wv+64)
  const int l    = tid & 63;                 // lane

  // this lane's gate-row: g = 16wg + (l&15) + 512*(l>>4)
  const int g = 16 * wg + (l & 15) + 512 * (l >> 4);

  // register-stationary recurrent weights: lane's row, wave's 64-k chunk
  float whh[64];
  {
    const float4* phh = (const float4*)(W_hh + (size_t)g * HDIM + (size_t)wv * 64);
#pragma unroll
    for (int j = 0; j < 16; ++j) {
      float4 v = phh[j];
      whh[4*j+0] = v.x; whh[4*j+1] = v.y; whh[4*j+2] = v.z; whh[4*j+3] = v.w;
    }
  }

  // gate identity (waves 0,1 act): unit gu, local batch gbl (0..3)
  const int gu = l & 15, gbl = l >> 4;
  const int unit = 16 * wg + gu;
  float c_state = 0.f;
  // xproj base for this gate thread (group = wv): [s][team][g][tb]
  const float* xpbase = xproj + (size_t)(16 * wg + gu) * 8 + (wv * 4 + gbl);

  for (int s = 0; s < S_LEN; ++s) {
    const int par = s & 1, par2 = (s + 1) & 1;

    // step-top prefetch: all 8 batches' tagged h loads issued at once
    ull pre0 = 0, pre1 = 0, pre2 = 0, pre3 = 0;
    ull pre4 = 0, pre5 = 0, pre6 = 0, pre7 = 0;
    const ull* hb0 = h_buf + (((size_t)par * TEAMS + team) * TB) * HDIM
                     + (size_t)64 * wv + l;
    if (s > 0) {
      pre0 = __hip_atomic_load(hb0 + 0 * HDIM, __ATOMIC_RELAXED, __HIP_MEMORY_SCOPE_AGENT);
      pre1 = __hip_atomic_load(hb0 + 1 * HDIM, __ATOMIC_RELAXED, __HIP_MEMORY_SCOPE_AGENT);
      pre2 = __hip_atomic_load(hb0 + 2 * HDIM, __ATOMIC_RELAXED, __HIP_MEMORY_SCOPE_AGENT);
      pre3 = __hip_atomic_load(hb0 + 3 * HDIM, __ATOMIC_RELAXED, __HIP_MEMORY_SCOPE_AGENT);
      pre4 = __hip_atomic_load(hb0 + 4 * HDIM, __ATOMIC_RELAXED, __HIP_MEMORY_SCOPE_AGENT);
      pre5 = __hip_atomic_load(hb0 + 5 * HDIM, __ATOMIC_RELAXED, __HIP_MEMORY_SCOPE_AGENT);
      pre6 = __hip_atomic_load(hb0 + 6 * HDIM, __ATOMIC_RELAXED, __HIP_MEMORY_SCOPE_AGENT);
      pre7 = __hip_atomic_load(hb0 + 7 * HDIM, __ATOMIC_RELAXED, __HIP_MEMORY_SCOPE_AGENT);
    }

#pragma unroll
    for (int G = 0; G < 2; ++G) {
      // gate wave for G prefetches its 4 xproj values (consumed after sync)
      float xv0, xv1, xv2, xv3;
      if (wv == G) {
        const float* p = xpbase + ((size_t)s * TEAMS + team) * (2048 * 8);
        xv0 = p[0]; xv1 = p[512 * 8]; xv2 = p[1024 * 8]; xv3 = p[1536 * 8];
      }

      float acc0 = 0.f, acc1 = 0.f, acc2 = 0.f, acc3 = 0.f;
      if (s > 0) {
        // use prefetched words; retry-loop fallback on stale tags (== r8)
        ull r0 = (G == 0) ? pre0 : pre4;
        ull r1 = (G == 0) ? pre1 : pre5;
        ull r2 = (G == 0) ? pre2 : pre6;
        ull r3 = (G == 0) ? pre3 : pre7;
        bool ok = ((int)(r0 >> 32) == s) & ((int)(r1 >> 32) == s) &
                  ((int)(r2 >> 32) == s) & ((int)(r3 >> 32) == s);
        if (!__all(ok)) {
          const ull* hb = hb0 + (size_t)(G * 4) * HDIM;
          int spins = 0;
          for (;;) {
            r0 = __hip_atomic_load(hb + 0 * HDIM, __ATOMIC_RELAXED, __HIP_MEMORY_SCOPE_AGENT);
            r1 = __hip_atomic_load(hb + 1 * HDIM, __ATOMIC_RELAXED, __HIP_MEMORY_SCOPE_AGENT);
            r2 = __hip_atomic_load(hb + 2 * HDIM, __ATOMIC_RELAXED, __HIP_MEMORY_SCOPE_AGENT);
            r3 = __hip_atomic_load(hb + 3 * HDIM, __ATOMIC_RELAXED, __HIP_MEMORY_SCOPE_AGENT);
            ok = ((int)(r0 >> 32) == s) & ((int)(r1 >> 32) == s) &
                 ((int)(r2 >> 32) == s) & ((int)(r3 >> 32) == s);
            if (__all(ok)) break;
            __builtin_amdgcn_s_sleep(1);
            if (++spins > (1 << 18)) break;    // hang guard only
          }
        }
        const int h0 = (int)(unsigned)r0, h1 = (int)(unsigned)r1;
        const int h2 = (int)(unsigned)r2, h3 = (int)(unsigned)r3;
        // dot via wave-broadcast readlane: VALU-pipe, no LDS
#pragma unroll
        for (int k = 0; k < 64; ++k) {
          const float wk = whh[k];
          acc0 = fmaf(wk, __int_as_float(__builtin_amdgcn_readlane(h0, k)), acc0);
          acc1 = fmaf(wk, __int_as_float(__builtin_amdgcn_readlane(h1, k)), acc1);
          acc2 = fmaf(wk, __int_as_float(__builtin_amdgcn_readlane(h2, k)), acc2);
          acc3 = fmaf(wk, __int_as_float(__builtin_amdgcn_readlane(h3, k)), acc3);
        }
      }

      // publish k-partials
      red[G][wv][0][l] = acc0;
      red[G][wv][1][l] = acc1;
      red[G][wv][2][l] = acc2;
      red[G][wv][3][l] = acc3;
      __syncthreads();

      // fused reduce + gates + exchange store: gate wave G only
      if (wv == G) {
        float z0 = xv0, z1 = xv1, z2 = xv2, z3 = xv3;
#pragma unroll
        for (int w2 = 0; w2 < 8; ++w2) {
          z0 += red[G][w2][gbl][gu +  0];
          z1 += red[G][w2][gbl][gu + 16];
          z2 += red[G][w2][gbl][gu + 32];
          z3 += red[G][w2][gbl][gu + 48];
        }
        float i_ = 1.f / (1.f + expf(-z0));
        float f_ = 1.f / (1.f + expf(-z1));
        float g_ = tanhf(z2);
        float o_ = 1.f / (1.f + expf(-z3));
        c_state = f_ * c_state + i_ * g_;
        float h_ = o_ * tanhf(c_state);
        // single 8B fire-and-forget message (tag = s+1 | h bits)
        ull pv = ((ull)(unsigned)(s + 1) << 32) | __float_as_uint(h_);
        __hip_atomic_store(
            &h_buf[(((size_t)par2 * TEAMS + team) * TB + G * 4 + gbl) * HDIM + unit],
            pv, __ATOMIC_RELAXED, __HIP_MEMORY_SCOPE_AGENT);
        states[((size_t)s * BATCH + team * TB + G * 4 + gbl) * HDIM + unit] = h_;
      }
      // no trailing barrier: next phase writes red[G^1]; red[G] is re-written
      // only after the NEXT phase's syncthreads (r8 transitive argument).
    }
  }
}

// ---------------- attention GEMM: tanh(states@W_word + b_word) @ w_proj ----------------
#define ATP 132
__global__ __launch_bounds__(256) void attn_gemm(
    const float* __restrict__ states, const float* __restrict__ W_word,
    const float* __restrict__ b_word, const float* __restrict__ w_proj,
    float* __restrict__ part) {
  __shared__ float At[16][ATP];   // A transposed tile [k][m]
  __shared__ float Bt[16][ATP];   // B tile [k][n]
  __shared__ float redl[128][17];

  const int tid = threadIdx.x;
  const int m0 = blockIdx.x * 128;   // token tile
  const int n0 = blockIdx.y * 128;   // tanh-dim tile
  const int ty = tid >> 4, tx = tid & 15;

  float acc[8][8];
#pragma unroll
  for (int i = 0; i < 8; ++i)
#pragma unroll
    for (int j = 0; j < 8; ++j) acc[i][j] = 0.f;

  for (int k0 = 0; k0 < 512; k0 += 16) {
#pragma unroll
    for (int it = 0; it < 2; ++it) {
      int m = (tid >> 2) + 64 * it;
      int kq = tid & 3;
      float4 v = *(const float4*)&states[(size_t)(m0 + m) * 512 + k0 + 4 * kq];
      At[4 * kq + 0][m] = v.x; At[4 * kq + 1][m] = v.y;
      At[4 * kq + 2][m] = v.z; At[4 * kq + 3][m] = v.w;
    }
#pragma unroll
    for (int it = 0; it < 2; ++it) {
      int kr = (tid >> 5) + 8 * it;
      int nq = tid & 31;
      float4 v = *(const float4*)&W_word[(size_t)(k0 + kr) * 512 + n0 + 4 * nq];
      *(float4*)&Bt[kr][4 * nq] = v;
    }
    __syncthreads();
#pragma unroll
    for (int kk = 0; kk < 16; ++kk) {
      float4 a0 = *(const float4*)&At[kk][ty * 8];
      float4 a1 = *(const float4*)&At[kk][ty * 8 + 4];
      float4 b0 = *(const float4*)&Bt[kk][tx * 8];
      float4 b1 = *(const float4*)&Bt[kk][tx * 8 + 4];
      float av[8] = {a0.x, a0.y, a0.z, a0.w, a1.x, a1.y, a1.z, a1.w};
      float bv[8] = {b0.x, b0.y, b0.z, b0.w, b1.x, b1.y, b1.z, b1.w};
#pragma unroll
      for (int i = 0; i < 8; ++i)
#pragma unroll
        for (int j = 0; j < 8; ++j) acc[i][j] = fmaf(av[i], bv[j], acc[i][j]);
    }
    __syncthreads();
  }
  float bw[8], wp[8];
  {
    float4 v0 = *(const float4*)&b_word[n0 + tx * 8];
    float4 v1 = *(const float4*)&b_word[n0 + tx * 8 + 4];
    bw[0]=v0.x; bw[1]=v0.y; bw[2]=v0.z; bw[3]=v0.w; bw[4]=v1.x; bw[5]=v1.y; bw[6]=v1.z; bw[7]=v1.w;
    float4 u0 = *(const float4*)&w_proj[n0 + tx * 8];
    float4 u1 = *(const float4*)&w_proj[n0 + tx * 8 + 4];
    wp[0]=u0.x; wp[1]=u0.y; wp[2]=u0.z; wp[3]=u0.w; wp[4]=u1.x; wp[5]=u1.y; wp[6]=u1.z; wp[7]=u1.w;
  }
#pragma unroll
  for (int i = 0; i < 8; ++i) {
    float rs = 0.f;
#pragma unroll
    for (int j = 0; j < 8; ++j) rs += tanhf(acc[i][j] + bw[j]) * wp[j];
    redl[ty * 8 + i][tx] = rs;
  }
  __syncthreads();
  if (tid < 128) {
    float ssum = 0.f;
#pragma unroll
    for (int x = 0; x < 16; ++x) ssum += redl[tid][x];
    part[(size_t)blockIdx.y * (S_LEN * BATCH) + m0 + tid] = ssum;
  }
}

// ---------------- phase A: per-(batch, S-slice) online-softmax partials ----------------
__global__ __launch_bounds__(256) void pool_partial(
    const float* __restrict__ part, const float* __restrict__ states,
    float* __restrict__ poolP, float* __restrict__ ml) {
  const int b = blockIdx.x >> 3;        // batch
  const int sl = blockIdx.x & 7;        // slice
  const int s0 = sl * SLICE_LEN;
  const int len = (sl == 7) ? (S_LEN - 7 * SLICE_LEN) : SLICE_LEN;
  const int tid = threadIdx.x;

  __shared__ float es[SLICE_LEN];
  __shared__ float redm[256];

  // scores for this slice
  float sc = -1e30f;
  if (tid < len) {
    const int t = (s0 + tid) * BATCH + b;
    sc = part[t] + part[S_LEN * BATCH + t] + part[2 * S_LEN * BATCH + t] +
         part[3 * S_LEN * BATCH + t];
  }
  redm[tid] = sc;
  __syncthreads();
  for (int o = 128; o > 0; o >>= 1) {
    if (tid < o) redm[tid] = fmaxf(redm[tid], redm[tid + o]);
    __syncthreads();
  }
  const float m_sl = redm[0];
  __syncthreads();
  float e = 0.f;
  if (tid < len) e = expf(sc - m_sl);
  if (tid < SLICE_LEN) es[tid] = (tid < len) ? e : 0.f;
  redm[tid] = e;
  __syncthreads();
  for (int o = 128; o > 0; o >>= 1) {
    if (tid < o) redm[tid] += redm[tid + o];
    __syncthreads();
  }
  if (tid == 0) {
    ml[(b * NSLICE + sl) * 2 + 0] = m_sl;
    ml[(b * NSLICE + sl) * 2 + 1] = redm[0];
  }
  __syncthreads();

  // partial weighted sum over this slice
  for (int h = tid; h < HDIM; h += 256) {
    float a = 0.f;
    for (int s = 0; s < len; ++s)
      a = fmaf(es[s], states[((size_t)(s0 + s) * BATCH + b) * HDIM + h], a);
    poolP[((size_t)b * NSLICE + sl) * HDIM + h] = a;
  }
}

// ---------------- phase B: merge slices + decode ----------------
__global__ __launch_bounds__(256) void pool_merge_decode(
    const float* __restrict__ poolP, const float* __restrict__ ml,
    const float* __restrict__ dec_W, const float* __restrict__ dec_b,
    float* __restrict__ out) {
  const int b = blockIdx.x;
  const int tid = threadIdx.x;
  __shared__ float pool[HDIM];
  __shared__ float redm[256];
  __shared__ float wsl[NSLICE];

  if (tid == 0) {
    float gmax = -1e30f;
#pragma unroll
    for (int i = 0; i < NSLICE; ++i) gmax = fmaxf(gmax, ml[(b * NSLICE + i) * 2]);
    float Z = 0.f;
#pragma unroll
    for (int i = 0; i < NSLICE; ++i) {
      float w = expf(ml[(b * NSLICE + i) * 2] - gmax);
      wsl[i] = w;
      Z = fmaf(ml[(b * NSLICE + i) * 2 + 1], w, Z);
    }
    redm[0] = 1.f / Z;
  }
  __syncthreads();
  const float inv = redm[0];

  for (int h = tid; h < HDIM; h += 256) {
    float a = 0.f;
#pragma unroll
    for (int i = 0; i < NSLICE; ++i)
      a = fmaf(wsl[i], poolP[((size_t)b * NSLICE + i) * HDIM + h], a);
    pool[h] = a * inv;
  }
  __syncthreads();
  const int lcls = tid >> 7, ch = tid & 127;
  float p = 0.f;
#pragma unroll
  for (int j = 0; j < 4; ++j)
    p = fmaf(pool[ch * 4 + j], dec_W[lcls * HDIM + ch * 4 + j], p);
  redm[tid] = p;
  __syncthreads();
  for (int o = 64; o > 0; o >>= 1) {
    if (ch < o) redm[tid] += redm[tid + o];
    __syncthreads();
  }
  if (ch == 0) out[b * 2 + lcls] = redm[tid] + dec_b[lcls];
}

extern "C" void kernel_launch(void* const* d_in, const int* in_sizes, int n_in,
                              void* d_out, int out_size, void* d_ws, size_t ws_size,
                              hipStream_t stream) {
  const int*   idx    = (const int*)d_in[0];
  // d_in[1] = text_lengths: unused by the reference
  const float* emb    = (const float*)d_in[2];
  const float* W_ih   = (const float*)d_in[3];
  const float* W_hh   = (const float*)d_in[4];
  const float* b_ih   = (const float*)d_in[5];
  const float* b_hh   = (const float*)d_in[6];
  const float* W_word = (const float*)d_in[7];
  const float* b_word = (const float*)d_in[8];
  const float* w_proj = (const float*)d_in[9];
  const float* dec_W  = (const float*)d_in[10];
  const float* dec_b  = (const float*)d_in[11];
  float* out = (float*)d_out;

  char* ws = (char*)d_ws;
  float* xproj  = (float*)ws;
  float* states = (float*)(ws + STATES_OFF);
  ull*   h_buf  = (ull*)(ws + HBUF_OFF);
  float* part   = (float*)(ws + PART_OFF);
  float* poolP  = (float*)(ws + POOLP_OFF);
  float* ml     = (float*)(ws + ML_OFF);

  // tags must start invalid each launch (prevents cross-replay tag collision)
  hipMemsetAsync(h_buf, 0, HBUF_BYTES, stream);

  // 1) x-projection for all timesteps (parallel GEMM, 67 GFLOP)
  xproj_gemm<<<dim3(250, 16), 256, 0, stream>>>(idx, emb, W_ih, b_ih, b_hh, xproj);

  // 2) recurrence (persistent cooperative, proven 256-block shape)
  void* args[] = {(void*)&xproj, (void*)&W_hh, (void*)&states, (void*)&h_buf};
  hipLaunchCooperativeKernel(lstm_persistent, dim3(NBLOCKS), dim3(NTHREADS), args, 0, stream);

  // 3) attention scores + 4) two-phase softmax/pool + decode
  attn_gemm<<<dim3(250, 4), 256, 0, stream>>>(states, W_word, b_word, w_proj, part);
  pool_partial<<<BATCH * NSLICE, 256, 0, stream>>>(part, states, poolP, ml);
  pool_merge_decode<<<BATCH, 256, 0, stream>>>(poolP, ml, dec_W, dec_b, out);
}